// Round 8
// baseline (16448.613 us; speedup 1.0000x reference)
//
#include <hip/hip_runtime.h>
#include <math.h>

constexpr int B   = 128;
constexpr int N   = 512;   // NNB + 2
constexpr int NNB = 510;
constexpr int D   = 128;
constexpr int FFH = 512;
constexpr int NL  = 3;

// ---------------------------------------------------------------------------
// XLA CPU/GPU f32 FastTanh (math_ops.cc EmitFastTanh, with_fma=true path):
// |x| < 0.0004 -> x; clamp to +-7.99881172180175781; rational 7/4 with FMA.
// __fmul_rn / __fadd_rn used where XLA emits unfused ops (hipcc contracts
// plain mul+add otherwise).
// ---------------------------------------------------------------------------
__device__ __forceinline__ float xla_fast_tanh(float x) {
    if (fabsf(x) < 0.0004f) return x;
    const float C = 7.99881172180175781f;
    float xc = fminf(fmaxf(x, -C), C);
    float x2 = __fmul_rn(xc, xc);
    float num = -2.76076847742355e-16f;
    num = __builtin_fmaf(x2, num, 2.00018790482477e-13f);
    num = __builtin_fmaf(x2, num, -8.60467152213735e-11f);
    num = __builtin_fmaf(x2, num, 5.12229709037114e-08f);
    num = __builtin_fmaf(x2, num, 1.48572235717979e-05f);
    num = __builtin_fmaf(x2, num, 6.37261928875436e-04f);
    num = __builtin_fmaf(x2, num, 4.89352455891786e-03f);
    num = __fmul_rn(xc, num);
    float den = 1.19825839466702e-06f;
    den = __builtin_fmaf(x2, den, 1.18534705686654e-04f);
    den = __builtin_fmaf(x2, den, 2.26843463243900e-03f);
    den = __builtin_fmaf(x2, den, 4.89352518554385e-03f);
    return num / den;
}

// ---------------------------------------------------------------------------
// build_x: one thread per (b,n,d), f64 math, f64 output.
// ---------------------------------------------------------------------------
__global__ __launch_bounds__(256) void k_build_x(
    const float* __restrict__ xy, const float* __restrict__ load,
    const float* __restrict__ demand, const float* __restrict__ mask,
    const float* __restrict__ embW, const float* __restrict__ embb,
    const float* __restrict__ wload, const float* __restrict__ wdem,
    const float* __restrict__ Wqf, const float* __restrict__ Wql,
    double* __restrict__ x)
{
    int gid = blockIdx.x * 256 + threadIdx.x;   // [0, B*N*D)
    int d  = gid & 127;
    int bn = gid >> 7;
    int b  = bn >> 9, n = bn & 511;
    double l = (double)load[b];
    double load3 = (l == 0.0) ? 1.0 : l;
    double x0 = (double)xy[(size_t)bn * 2], x1 = (double)xy[(size_t)bn * 2 + 1];
    double outv;
    if (n >= 2) {
        float m = mask[(size_t)b * N + n];
        if (m < 0.f) {
            outv = 0.0;
        } else {
            double fl = x0 * (double)embW[d] + x1 * (double)embW[D + d] + (double)embb[d];
            double dm = (double)demand[(size_t)b * NNB + (n - 2)] / load3;
            dm = fmin(fmax(dm, 0.0), 1.0);
            outv = fl + dm * (double)wdem[d];
        }
    } else {
        const float* W = (n == 0) ? Wqf : Wql;
        double acc = 0.0;
        for (int e = 0; e < D; ++e) {
            double fe = x0 * (double)embW[e] + x1 * (double)embW[D + e] + (double)embb[e];
            acc += fe * (double)W[(size_t)e * D + d];
        }
        outv = acc + load3 * (double)wload[d];
    }
    x[(size_t)bn * D + d] = outv;
}

// ---------------------------------------------------------------------------
// GEMM: C[m,n] = sum_k A[m,k]*W[k,n] (+bias,+relu), f64 accumulation.
// ---------------------------------------------------------------------------
template<typename TA, typename TC, int KDIM, int NCdim, int MROWS, bool BIAS, bool RELU>
__global__ __launch_bounds__(512) void k_gemm(
    const TA* __restrict__ A, const float* __restrict__ W,
    const float* __restrict__ bias, TC* __restrict__ C)
{
    __shared__ TA As[MROWS * KDIM];
    const int n = threadIdx.x;                      // [0, NCdim)
    const size_t m0 = (size_t)blockIdx.x * MROWS;
    for (int idx = n; idx < MROWS * KDIM; idx += NCdim)
        As[idx] = A[m0 * KDIM + idx];
    __syncthreads();
    double acc[MROWS];
    #pragma unroll
    for (int m = 0; m < MROWS; ++m) acc[m] = 0.0;
    for (int k = 0; k < KDIM; ++k) {
        double wk = (double)W[(size_t)k * NCdim + n];
        #pragma unroll
        for (int m = 0; m < MROWS; ++m)
            acc[m] += (double)As[m * KDIM + k] * wk;
    }
    #pragma unroll
    for (int m = 0; m < MROWS; ++m) {
        double o = acc[m] + (BIAS ? (double)bias[n] : 0.0);
        if (RELU) o = fmax(o, 0.0);
        C[(m0 + m) * NCdim + n] = (TC)o;
    }
}

// ---------------------------------------------------------------------------
// Column max of k over s (axis=1) per (b,d); then ek = exp(k - max) in place.
// ---------------------------------------------------------------------------
__global__ __launch_bounds__(256) void k_colmax(
    const double* __restrict__ k, double* __restrict__ kmax)
{
    int gid = blockIdx.x * 256 + threadIdx.x;   // [0, B*D)
    int b = gid >> 7, d = gid & 127;
    const double* kp = k + (size_t)b * N * D + d;
    double m = -1e300;
    for (int s = 0; s < N; ++s) m = fmax(m, kp[(size_t)s * D]);
    kmax[gid] = m;
}

__global__ __launch_bounds__(256) void k_ek(
    double* __restrict__ k, const double* __restrict__ kmax)
{
    size_t gid = (size_t)blockIdx.x * 256 + threadIdx.x;   // [0, B*N*D)
    int d = (int)(gid & 127);
    int b = (int)(gid >> 16);                               // N*D = 2^16
    k[gid] = exp(k[gid] - kmax[b * 128 + d]);
}

// ---------------------------------------------------------------------------
// Attention with on-the-fly q: block per (b,t) row, thread = d.
// ews f64 in LDS (fused row-max), q_d = x_row @ Wq[:,d] in f64,
// att = (sigmoid(q)*num)/den  (left-to-right like the reference).
// ---------------------------------------------------------------------------
template<typename TATT>
__global__ __launch_bounds__(128) void k_attn_q(
    const float* __restrict__ pdist, const float* __restrict__ mask,
    const double* __restrict__ x, const float* __restrict__ Wql,
    const double* __restrict__ ek, const double* __restrict__ v,
    const int* __restrict__ nnum, const float* __restrict__ aAttn, int l,
    TATT* __restrict__ att)
{
    __shared__ double xrow[128];
    __shared__ double ews[512];
    __shared__ double red[128];
    int bt = blockIdx.x;            // b*512 + t
    int b = bt >> 9, d = threadIdx.x;
    xrow[d] = x[(size_t)bt * 128 + d];
    double la = -log2((double)nnum[b]) * (double)aAttn[l];
    const float* pd = pdist + (size_t)bt * 512;
    const float* mk = mask + (size_t)b * 512;
    double tm = -1e300;
    for (int i = 0; i < 4; ++i) {
        int s = d + i * 128;
        double w = la * (double)pd[s] + (double)mk[s];
        ews[s] = w;
        tm = fmax(tm, w);
    }
    red[d] = tm;
    __syncthreads();
    for (int s2 = 64; s2; s2 >>= 1) {
        if (d < s2) red[d] = fmax(red[d], red[d + s2]);
        __syncthreads();
    }
    double wm = red[0];
    for (int i = 0; i < 4; ++i) {
        int s = d + i * 128;
        ews[s] = exp(ews[s] - wm);      // each slot owned by this thread
    }
    double qd = 0.0;                     // x row visible since first sync
    for (int e = 0; e < 128; ++e)
        qd += xrow[e] * (double)Wql[(size_t)e * 128 + d];
    __syncthreads();                     // ews complete
    const double* ekp = ek + (size_t)b * N * D + d;
    const double* vp  = v  + (size_t)b * N * D + d;
    double num = 0.0, den = 0.0;
    for (int s = 0; s < N; ++s) {
        double we = ews[s] * ekp[(size_t)s * D];
        num += we * vp[(size_t)s * D];
        den += we;
    }
    double sg = 1.0 / (1.0 + exp(-qd));
    att[(size_t)bt * 128 + d] = (TATT)((sg * num) / den);
}

// ---------------------------------------------------------------------------
// x = LayerNorm(x + b2)*g + be, block per row, f64, in place.
// ---------------------------------------------------------------------------
template<typename TB2>
__global__ __launch_bounds__(128) void k_ln(
    double* __restrict__ x, const TB2* __restrict__ b2,
    const float* __restrict__ g, const float* __restrict__ be)
{
    __shared__ double red[128];
    int row = blockIdx.x, d = threadIdx.x;
    size_t off = (size_t)row * 128 + d;
    double xv = x[off] + (double)b2[off];
    red[d] = xv;
    __syncthreads();
    for (int s = 64; s; s >>= 1) { if (d < s) red[d] += red[d + s]; __syncthreads(); }
    double mean = red[0] * (1.0 / 128.0);
    __syncthreads();
    double dx = xv - mean;
    red[d] = dx * dx;
    __syncthreads();
    for (int s = 64; s; s >>= 1) { if (d < s) red[d] += red[d + s]; __syncthreads(); }
    double var = red[0] * (1.0 / 128.0);
    x[off] = dx * (1.0 / sqrt(var + 1e-5)) * (double)g[d] + (double)be[d];
}

// ---------------------------------------------------------------------------
// Final head: s_n in f64, then XLA-f32 semantics for tanh/score/softmax/argmax.
// Ties at the FastTanh clamp produce identical f32 bits -> first-occurrence
// argmax replicates the jax/XLA reference's selection among saturated scores.
// ---------------------------------------------------------------------------
__global__ __launch_bounds__(512) void k_final(
    const double* __restrict__ x, const float* __restrict__ pdist,
    const float* __restrict__ mask, const int* __restrict__ nnum,
    const int* __restrict__ nidx, const float* __restrict__ aCom,
    float* __restrict__ out)
{
    __shared__ float  sc[512];
    __shared__ float  ee[512];
    __shared__ double qo[128];
    int b = blockIdx.x, tid = threadIdx.x;
    const double* xb = x + (size_t)b * N * D;
    if (tid < 128) qo[tid] = xb[tid] + xb[128 + tid];
    __syncthreads();
    if (tid < NNB) {
        const double* xr = xb + (size_t)(2 + tid) * 128;
        double s = 0.0;
        for (int dd = 0; dd < 128; ++dd) s += qo[dd] * xr[dd];
        double lg = -log2((double)nnum[b]);
        s = s / 11.313708498984761
          + (double)aCom[0] * lg * (double)pdist[((size_t)b * 512 + 1) * 512 + 2 + tid];
        float t = xla_fast_tanh((float)s);
        sc[tid] = __fadd_rn(__fmul_rn(10.0f, t),
                            mask[(size_t)b * 512 + 2 + tid]);
    }
    __syncthreads();
    if (tid == 0) {
        float m = -3.4e38f;
        for (int n2 = 0; n2 < NNB; ++n2) m = fmaxf(m, sc[n2]);
        float S = 0.f;
        for (int n2 = 0; n2 < NNB; ++n2) {
            float e = expf(__fadd_rn(sc[n2], -m));
            ee[n2] = e;
            S = __fadd_rn(S, e);
        }
        float bestp = -1.f; int sel = 0;
        for (int n2 = 0; n2 < NNB; ++n2) {
            float p = ee[n2] / S;
            if (p > bestp) { bestp = p; sel = n2; }
        }
        out[b]     = (float)nidx[(size_t)b * NNB + sel];
        out[B + b] = bestp;
    }
}

// ---------------------------------------------------------------------------
extern "C" void kernel_launch(void* const* d_in, const int* in_sizes, int n_in,
                              void* d_out, int out_size, void* d_ws, size_t ws_size,
                              hipStream_t stream)
{
    const float* xy     = (const float*)d_in[0];
    const float* load   = (const float*)d_in[1];
    const float* demand = (const float*)d_in[2];
    const float* mask   = (const float*)d_in[3];
    const float* pdist  = (const float*)d_in[4];
    const int*   nnum   = (const int*)d_in[5];
    const int*   nidx   = (const int*)d_in[6];
    const float* embW   = (const float*)d_in[7];
    const float* embb   = (const float*)d_in[8];
    const float* wload  = (const float*)d_in[9];
    const float* wdem   = (const float*)d_in[10];
    const float* Wqf    = (const float*)d_in[11];
    const float* Wql    = (const float*)d_in[12];
    const float* aCom   = (const float*)d_in[13];
    const float* Wq     = (const float*)d_in[14];
    const float* Wk     = (const float*)d_in[15];
    const float* Wv     = (const float*)d_in[16];
    const float* aAttn  = (const float*)d_in[17];
    const float* ln1g   = (const float*)d_in[18];
    const float* ln1b   = (const float*)d_in[19];
    const float* ln2g   = (const float*)d_in[20];
    const float* ln2b   = (const float*)d_in[21];
    const float* fW1    = (const float*)d_in[22];
    const float* fb1    = (const float*)d_in[23];
    const float* fW2    = (const float*)d_in[24];
    const float* fb2    = (const float*)d_in[25];
    float* out = (float*)d_out;

    // ---- workspace ---------------------------------------------------------
    const size_t SZ = (size_t)B * N * D;           // 8388608 elements
    double* xbuf = (double*)d_ws;                  // f64 [  0, 64M)
    double* kbuf = xbuf + SZ;                      // f64 [ 64,128M)  k -> ek
    double* vbuf = kbuf + SZ;                      // f64 [128,192M)
    void*   areg = (void*)(vbuf + SZ);             // att region [192, ...)
    double* att64 = (double*)areg;
    float*  att32 = (float*)areg;
    double* kmaxd = (double*)areg;                 // 128 KiB borrow (pre-attn)
    double* ffh   = (double*)areg;                 // FF chunk hidden (16 MB)
    const int RCH = 4096;                          // FF chunk rows
    double* aux   = ffh + (size_t)RCH * FFH;       // FF chunk out (4 MB)

    const bool full64 = (ws_size >= 268435456ULL); // 256 MiB
    const int M = B * N;                           // 65536

    k_build_x<<<(B * N * D) / 256, 256, 0, stream>>>(
        xy, load, demand, mask, embW, embb, wload, wdem, Wqf, Wql, xbuf);

    for (int l = 0; l < NL; ++l) {
        k_gemm<double, double, 128, 128, 16, false, false><<<M / 16, 128, 0, stream>>>(
            xbuf, Wk + (size_t)l * D * D, nullptr, kbuf);
        k_colmax<<<(B * D) / 256, 256, 0, stream>>>(kbuf, kmaxd);
        k_ek<<<(int)(SZ / 256), 256, 0, stream>>>(kbuf, kmaxd);
        k_gemm<double, double, 128, 128, 16, false, false><<<M / 16, 128, 0, stream>>>(
            xbuf, Wv + (size_t)l * D * D, nullptr, vbuf);
        if (full64) {
            k_attn_q<double><<<B * N, 128, 0, stream>>>(
                pdist, mask, xbuf, Wq + (size_t)l * D * D, kbuf, vbuf, nnum, aAttn, l, att64);
            k_ln<double><<<M, 128, 0, stream>>>(xbuf, att64, ln1g + l * D, ln1b + l * D);
        } else {
            k_attn_q<float><<<B * N, 128, 0, stream>>>(
                pdist, mask, xbuf, Wq + (size_t)l * D * D, kbuf, vbuf, nnum, aAttn, l, att32);
            k_ln<float><<<M, 128, 0, stream>>>(xbuf, att32, ln1g + l * D, ln1b + l * D);
        }
        for (int c = 0; c < M / RCH; ++c) {
            double* xc = xbuf + (size_t)c * RCH * D;
            k_gemm<double, double, 128, 512, 16, true, true><<<RCH / 16, 512, 0, stream>>>(
                xc, fW1 + (size_t)l * D * FFH, fb1 + l * FFH, ffh);
            k_gemm<double, double, 512, 128, 8, true, false><<<RCH / 8, 128, 0, stream>>>(
                ffh, fW2 + (size_t)l * FFH * D, fb2 + l * D, aux);
            k_ln<double><<<RCH, 128, 0, stream>>>(xc, aux, ln2g + l * D, ln2b + l * D);
        }
    }
    k_final<<<B, 512, 0, stream>>>(xbuf, pdist, mask, nnum, nidx, aCom, out);
}

// Round 9
// 2524.333 us; speedup vs baseline: 6.5160x; 6.5160x over previous
//
#include <hip/hip_runtime.h>
#include <math.h>

constexpr int B   = 128;
constexpr int N   = 512;   // NNB + 2
constexpr int NNB = 510;
constexpr int D   = 128;
constexpr int FFH = 512;
constexpr int NL  = 3;

__device__ __forceinline__ float sigmoidf_(float x) { return 1.f / (1.f + expf(-x)); }

// ---------------------------------------------------------------------------
// XLA f32 FastTanh (math_ops.cc EmitFastTanh, with_fma path) — exact tie
// structure of the jax reference's tanh. DO NOT TOUCH (r8-validated).
// ---------------------------------------------------------------------------
__device__ __forceinline__ float xla_fast_tanh(float x) {
    if (fabsf(x) < 0.0004f) return x;
    const float C = 7.99881172180175781f;
    float xc = fminf(fmaxf(x, -C), C);
    float x2 = __fmul_rn(xc, xc);
    float num = -2.76076847742355e-16f;
    num = __builtin_fmaf(x2, num, 2.00018790482477e-13f);
    num = __builtin_fmaf(x2, num, -8.60467152213735e-11f);
    num = __builtin_fmaf(x2, num, 5.12229709037114e-08f);
    num = __builtin_fmaf(x2, num, 1.48572235717979e-05f);
    num = __builtin_fmaf(x2, num, 6.37261928875436e-04f);
    num = __builtin_fmaf(x2, num, 4.89352455891786e-03f);
    num = __fmul_rn(xc, num);
    float den = 1.19825839466702e-06f;
    den = __builtin_fmaf(x2, den, 1.18534705686654e-04f);
    den = __builtin_fmaf(x2, den, 2.26843463243900e-03f);
    den = __builtin_fmaf(x2, den, 4.89352518554385e-03f);
    return num / den;
}

// ---------------------------------------------------------------------------
// Build x (B,N,D) f32: rows 0/1 q_first/q_last (matvec), rows 2.. neighbors.
// ---------------------------------------------------------------------------
__global__ __launch_bounds__(128) void build_x_kernel(
    const float* __restrict__ xy, const float* __restrict__ load,
    const float* __restrict__ demand, const float* __restrict__ mask,
    const float* __restrict__ embW, const float* __restrict__ embb,
    const float* __restrict__ wload, const float* __restrict__ wdem,
    const float* __restrict__ Wqf, const float* __restrict__ Wql,
    float* __restrict__ x)
{
    __shared__ float fln[128];
    const int bn = blockIdx.x;
    const int b  = bn >> 9;
    const int n  = bn & 511;
    const int d  = threadIdx.x;
    float l = load[b];
    float load3 = (l == 0.f) ? 1.f : l;

    if (n >= 2) {
        const int j = n - 2;
        float m = mask[(size_t)b * N + n];
        float out = 0.f;
        if (!(m < 0.f)) {
            float x0 = xy[(size_t)bn * 2 + 0];
            float x1 = xy[(size_t)bn * 2 + 1];
            float fl = x0 * embW[d] + x1 * embW[D + d] + embb[d];
            float dm = demand[(size_t)b * NNB + j] / load3;
            dm = fminf(fmaxf(dm, 0.f), 1.f);
            out = fl + dm * wdem[d];
        }
        x[(size_t)bn * D + d] = out;
    } else {
        float x0 = xy[(size_t)bn * 2 + 0];
        float x1 = xy[(size_t)bn * 2 + 1];
        fln[d] = x0 * embW[d] + x1 * embW[D + d] + embb[d];
        __syncthreads();
        const float* W = (n == 0) ? Wqf : Wql;
        float acc = 0.f;
        #pragma unroll 8
        for (int e = 0; e < D; ++e) acc = fmaf(fln[e], W[(size_t)e * D + d], acc);
        x[(size_t)bn * D + d] = acc + load3 * wload[d];
    }
}

// ---------------------------------------------------------------------------
// Tiled f32 GEMM: C[M,Nc] = A[M,K] @ W[K,Nc] (+bias,+relu).
// BLK_M=64, BLK_N=128, BLK_K=32, 256 threads, 8x4 acc/thread.
// ---------------------------------------------------------------------------
template<bool BIAS, bool RELU>
__global__ __launch_bounds__(256) void gemm_f32(
    const float* __restrict__ A, const float* __restrict__ W,
    const float* __restrict__ bias, float* __restrict__ C,
    int M, int K, int Nc)
{
    __shared__ float As[64][40];
    __shared__ float Ws[32][132];
    const int m0 = blockIdx.x * 64;
    const int n0 = blockIdx.y * 128;
    const int tid = threadIdx.x;
    const int tc = tid & 31;
    const int tr = tid >> 5;

    float4 acc[8];
    #pragma unroll
    for (int r = 0; r < 8; ++r) acc[r] = make_float4(0.f, 0.f, 0.f, 0.f);

    for (int kt = 0; kt < K; kt += 32) {
        #pragma unroll
        for (int i = 0; i < 2; ++i) {
            int f = tid + i * 256;
            int r = f >> 3, c4 = (f & 7) * 4;
            float4 av = *(const float4*)&A[(size_t)(m0 + r) * K + kt + c4];
            *(float4*)&As[r][c4] = av;
        }
        #pragma unroll
        for (int i = 0; i < 4; ++i) {
            int f = tid + i * 256;
            int r = f >> 5, c4 = (f & 31) * 4;
            float4 wv = *(const float4*)&W[(size_t)(kt + r) * Nc + n0 + c4];
            *(float4*)&Ws[r][c4] = wv;
        }
        __syncthreads();
        #pragma unroll
        for (int kk = 0; kk < 32; kk += 4) {
            float4 w0 = *(float4*)&Ws[kk + 0][tc * 4];
            float4 w1 = *(float4*)&Ws[kk + 1][tc * 4];
            float4 w2 = *(float4*)&Ws[kk + 2][tc * 4];
            float4 w3 = *(float4*)&Ws[kk + 3][tc * 4];
            #pragma unroll
            for (int r = 0; r < 8; ++r) {
                float4 a4 = *(float4*)&As[tr * 8 + r][kk];
                acc[r].x = fmaf(a4.x, w0.x, acc[r].x); acc[r].x = fmaf(a4.y, w1.x, acc[r].x);
                acc[r].x = fmaf(a4.z, w2.x, acc[r].x); acc[r].x = fmaf(a4.w, w3.x, acc[r].x);
                acc[r].y = fmaf(a4.x, w0.y, acc[r].y); acc[r].y = fmaf(a4.y, w1.y, acc[r].y);
                acc[r].y = fmaf(a4.z, w2.y, acc[r].y); acc[r].y = fmaf(a4.w, w3.y, acc[r].y);
                acc[r].z = fmaf(a4.x, w0.z, acc[r].z); acc[r].z = fmaf(a4.y, w1.z, acc[r].z);
                acc[r].z = fmaf(a4.z, w2.z, acc[r].z); acc[r].z = fmaf(a4.w, w3.z, acc[r].z);
                acc[r].w = fmaf(a4.x, w0.w, acc[r].w); acc[r].w = fmaf(a4.y, w1.w, acc[r].w);
                acc[r].w = fmaf(a4.z, w2.w, acc[r].w); acc[r].w = fmaf(a4.w, w3.w, acc[r].w);
            }
        }
        __syncthreads();
    }

    float4 bv = make_float4(0.f, 0.f, 0.f, 0.f);
    if (BIAS) bv = *(const float4*)&bias[n0 + tc * 4];
    #pragma unroll
    for (int r = 0; r < 8; ++r) {
        float4 o = acc[r];
        if (BIAS) { o.x += bv.x; o.y += bv.y; o.z += bv.z; o.w += bv.w; }
        if (RELU) {
            o.x = fmaxf(o.x, 0.f); o.y = fmaxf(o.y, 0.f);
            o.z = fmaxf(o.z, 0.f); o.w = fmaxf(o.w, 0.f);
        }
        *(float4*)&C[(size_t)(m0 + tr * 8 + r) * Nc + n0 + tc * 4] = o;
    }
}

// ---------------------------------------------------------------------------
// Column-max of k over s (axis=1), two stages; then k := exp(k-colmax) in place.
// ---------------------------------------------------------------------------
__global__ __launch_bounds__(128) void colmax_part(
    const float* __restrict__ k, float* __restrict__ part)
{
    int b = blockIdx.x >> 3, c = blockIdx.x & 7, d = threadIdx.x;
    const float* kp = k + ((size_t)b * N + c * 64) * D + d;
    float m = -3.4e38f;
    #pragma unroll 8
    for (int s = 0; s < 64; ++s) m = fmaxf(m, kp[(size_t)s * D]);
    part[(size_t)blockIdx.x * D + d] = m;
}

__global__ __launch_bounds__(128) void ek_inplace(
    float* __restrict__ k, const float* __restrict__ part)
{
    int b = blockIdx.x >> 3, c = blockIdx.x & 7, d = threadIdx.x;
    float m = -3.4e38f;
    #pragma unroll
    for (int j = 0; j < 8; ++j) m = fmaxf(m, part[((size_t)b * 8 + j) * D + d]);
    float* kp = k + ((size_t)b * N + c * 64) * D + d;
    for (int s = 0; s < 64; ++s)
        kp[(size_t)s * D] = expf(kp[(size_t)s * D] - m);
}

// ---------------------------------------------------------------------------
// Fused AAFM attention, per (b, 32-row tile): ew=exp(w-rowmax) in LDS,
// num/den = ew @ [ek*v ; ek] streamed from global, att=(sig(q)*num)/den.
// ---------------------------------------------------------------------------
__global__ __launch_bounds__(256) void attn_kernel(
    const float* __restrict__ pdist, const float* __restrict__ mask,
    const float* __restrict__ ek, const float* __restrict__ v,
    const float* __restrict__ q,
    const int* __restrict__ nnum, const float* __restrict__ alphaAttn, int layer,
    float* __restrict__ att)
{
    __shared__ float ew[32][512];
    __shared__ float red8[32][8];
    __shared__ float rmax[32];
    const int bt = blockIdx.x;
    const int b  = bt >> 4;
    const int t0 = (bt & 15) * 32;
    const int tid = threadIdx.x;
    const float la = -log2f((float)nnum[b]) * alphaAttn[layer];
    const float* pd = pdist + ((size_t)b * N + t0) * N;
    const float* mk = mask + (size_t)b * N;

    #pragma unroll
    for (int i = 0; i < 16; ++i) {
        int f = tid + i * 256;
        int r = f >> 7, s4 = (f & 127) * 4;
        float4 p = *(const float4*)&pd[(size_t)r * N + s4];
        float4 m = *(const float4*)&mk[s4];
        float4 w;
        w.x = fmaf(la, p.x, m.x); w.y = fmaf(la, p.y, m.y);
        w.z = fmaf(la, p.z, m.z); w.w = fmaf(la, p.w, m.w);
        *(float4*)&ew[r][s4] = w;
    }
    __syncthreads();
    {
        int r = tid >> 3, seg = tid & 7;
        float m = -3.4e38f;
        const float* row = &ew[r][seg * 64];
        #pragma unroll 8
        for (int j = 0; j < 64; ++j) m = fmaxf(m, row[j]);
        red8[r][seg] = m;
    }
    __syncthreads();
    if (tid < 32) {
        float m = red8[tid][0];
        #pragma unroll
        for (int j = 1; j < 8; ++j) m = fmaxf(m, red8[tid][j]);
        rmax[tid] = m;
    }
    __syncthreads();
    #pragma unroll
    for (int i = 0; i < 16; ++i) {
        int f = tid + i * 256;
        int r = f >> 7, s4 = (f & 127) * 4;
        float m = rmax[r];
        float4 w = *(float4*)&ew[r][s4];
        w.x = expf(w.x - m); w.y = expf(w.y - m);
        w.z = expf(w.z - m); w.w = expf(w.w - m);
        *(float4*)&ew[r][s4] = w;
    }
    __syncthreads();

    const int tc = tid & 31, tr = tid >> 5;   // rows tr*4..+4, cols tc*4..+4
    float4 num[4], den[4];
    #pragma unroll
    for (int r = 0; r < 4; ++r) {
        num[r] = make_float4(0.f, 0.f, 0.f, 0.f);
        den[r] = make_float4(0.f, 0.f, 0.f, 0.f);
    }
    const size_t brow = (size_t)b * N;
    const float* ekp = ek + brow * D + tc * 4;
    const float* vp  = v  + brow * D + tc * 4;
    for (int s = 0; s < N; s += 2) {
        float4 e0 = *(const float4*)&ekp[(size_t)s * D];
        float4 u0 = *(const float4*)&vp [(size_t)s * D];
        float4 e1 = *(const float4*)&ekp[(size_t)(s + 1) * D];
        float4 u1 = *(const float4*)&vp [(size_t)(s + 1) * D];
        #pragma unroll
        for (int r = 0; r < 4; ++r) {
            float a0 = ew[tr * 4 + r][s];
            float a1 = ew[tr * 4 + r][s + 1];
            float4 ae0, ae1;
            ae0.x = a0 * e0.x; ae0.y = a0 * e0.y; ae0.z = a0 * e0.z; ae0.w = a0 * e0.w;
            ae1.x = a1 * e1.x; ae1.y = a1 * e1.y; ae1.z = a1 * e1.z; ae1.w = a1 * e1.w;
            num[r].x = fmaf(ae0.x, u0.x, num[r].x); num[r].x = fmaf(ae1.x, u1.x, num[r].x);
            num[r].y = fmaf(ae0.y, u0.y, num[r].y); num[r].y = fmaf(ae1.y, u1.y, num[r].y);
            num[r].z = fmaf(ae0.z, u0.z, num[r].z); num[r].z = fmaf(ae1.z, u1.z, num[r].z);
            num[r].w = fmaf(ae0.w, u0.w, num[r].w); num[r].w = fmaf(ae1.w, u1.w, num[r].w);
            den[r].x += ae0.x + ae1.x;
            den[r].y += ae0.y + ae1.y;
            den[r].z += ae0.z + ae1.z;
            den[r].w += ae0.w + ae1.w;
        }
    }
    #pragma unroll
    for (int r = 0; r < 4; ++r) {
        size_t off = (brow + t0 + tr * 4 + r) * D + tc * 4;
        float4 qq = *(const float4*)&q[off];
        float4 o;
        o.x = sigmoidf_(qq.x) * num[r].x / den[r].x;
        o.y = sigmoidf_(qq.y) * num[r].y / den[r].y;
        o.z = sigmoidf_(qq.z) * num[r].z / den[r].z;
        o.w = sigmoidf_(qq.w) * num[r].w / den[r].w;
        *(float4*)&att[off] = o;
    }
}

// ---------------------------------------------------------------------------
// out = LayerNorm(a + b) * g + be. Wave per row, two-pass variance.
// ---------------------------------------------------------------------------
__global__ __launch_bounds__(256) void ln_kernel(
    const float* a, const float* b2, const float* g, const float* be, float* out)
{
    int w = threadIdx.x >> 6, lane = threadIdx.x & 63;
    size_t row = (size_t)blockIdx.x * 4 + w;
    size_t base = row * D + lane * 2;
    float2 av = *(const float2*)&a[base];
    float2 bv = *(const float2*)&b2[base];
    float x0 = av.x + bv.x, x1 = av.y + bv.y;
    float s = x0 + x1;
    #pragma unroll
    for (int off = 32; off > 0; off >>= 1) s += __shfl_xor(s, off);
    float mean = s * (1.f / 128.f);
    float d0 = x0 - mean, d1 = x1 - mean;
    float ss = d0 * d0 + d1 * d1;
    #pragma unroll
    for (int off = 32; off > 0; off >>= 1) ss += __shfl_xor(ss, off);
    float rs = rsqrtf(ss * (1.f / 128.f) + 1e-5f);
    float2 o;
    o.x = d0 * rs * g[lane * 2]     + be[lane * 2];
    o.y = d1 * rs * g[lane * 2 + 1] + be[lane * 2 + 1];
    *(float2*)&out[base] = o;
}

// ---------------------------------------------------------------------------
// Final head (r8-validated): f64 score dot, XLA-f32 FastTanh, f32 softmax,
// first-occurrence argmax over p. x input is f32 now.
// ---------------------------------------------------------------------------
__global__ __launch_bounds__(512) void k_final(
    const float* __restrict__ x, const float* __restrict__ pdist,
    const float* __restrict__ mask, const int* __restrict__ nnum,
    const int* __restrict__ nidx, const float* __restrict__ aCom,
    float* __restrict__ out)
{
    __shared__ float  sc[512];
    __shared__ float  ee[512];
    __shared__ double qo[128];
    int b = blockIdx.x, tid = threadIdx.x;
    const float* xb = x + (size_t)b * N * D;
    if (tid < 128) qo[tid] = (double)xb[tid] + (double)xb[128 + tid];
    __syncthreads();
    if (tid < NNB) {
        const float* xr = xb + (size_t)(2 + tid) * 128;
        double s = 0.0;
        for (int dd = 0; dd < 128; ++dd) s += qo[dd] * (double)xr[dd];
        double lg = -log2((double)nnum[b]);
        s = s / 11.313708498984761
          + (double)aCom[0] * lg * (double)pdist[((size_t)b * 512 + 1) * 512 + 2 + tid];
        float t = xla_fast_tanh((float)s);
        sc[tid] = __fadd_rn(__fmul_rn(10.0f, t),
                            mask[(size_t)b * 512 + 2 + tid]);
    }
    __syncthreads();
    if (tid == 0) {
        float m = -3.4e38f;
        for (int n2 = 0; n2 < NNB; ++n2) m = fmaxf(m, sc[n2]);
        float S = 0.f;
        for (int n2 = 0; n2 < NNB; ++n2) {
            float e = expf(__fadd_rn(sc[n2], -m));
            ee[n2] = e;
            S = __fadd_rn(S, e);
        }
        float bestp = -1.f; int sel = 0;
        for (int n2 = 0; n2 < NNB; ++n2) {
            float p = ee[n2] / S;
            if (p > bestp) { bestp = p; sel = n2; }
        }
        out[b]     = (float)nidx[(size_t)b * NNB + sel];
        out[B + b] = bestp;
    }
}

// ---------------------------------------------------------------------------
extern "C" void kernel_launch(void* const* d_in, const int* in_sizes, int n_in,
                              void* d_out, int out_size, void* d_ws, size_t ws_size,
                              hipStream_t stream)
{
    const float* xy     = (const float*)d_in[0];
    const float* load   = (const float*)d_in[1];
    const float* demand = (const float*)d_in[2];
    const float* mask   = (const float*)d_in[3];
    const float* pdist  = (const float*)d_in[4];
    const int*   nnum   = (const int*)d_in[5];
    const int*   nidx   = (const int*)d_in[6];
    const float* embW   = (const float*)d_in[7];
    const float* embb   = (const float*)d_in[8];
    const float* wload  = (const float*)d_in[9];
    const float* wdem   = (const float*)d_in[10];
    const float* Wqf    = (const float*)d_in[11];
    const float* Wql    = (const float*)d_in[12];
    const float* aCom   = (const float*)d_in[13];
    const float* Wq     = (const float*)d_in[14];
    const float* Wk     = (const float*)d_in[15];
    const float* Wv     = (const float*)d_in[16];
    const float* aAttn  = (const float*)d_in[17];
    const float* ln1g   = (const float*)d_in[18];
    const float* ln1b   = (const float*)d_in[19];
    const float* ln2g   = (const float*)d_in[20];
    const float* ln2b   = (const float*)d_in[21];
    const float* fW1    = (const float*)d_in[22];
    const float* fb1    = (const float*)d_in[23];
    const float* fW2    = (const float*)d_in[24];
    const float* fb2    = (const float*)d_in[25];
    float* out = (float*)d_out;

    // Workspace: 5*SZ f32 = 160 MB (ws_size >= 224 MB verified in r6 sentinels).
    float* ws = (float*)d_ws;
    const size_t SZ = (size_t)B * N * D;      // 8388608 floats
    float* xbuf = ws;                         // [0..1)
    float* qbuf = ws + SZ;                    // [1..2)
    float* kbuf = ws + 2 * SZ;                // [2..3)  (becomes ek in place)
    float* vbuf = ws + 3 * SZ;                // [3..4)
    float* wbuf = ws + 4 * SZ;                // [4..5)  attention output
    float* part = qbuf;                       // colmax partials (pre-q-gemm)
    float* bigh = qbuf;                       // ff hidden half: 2*SZ over [1..3)
    float* aux  = vbuf;                       // ff output: 1*SZ over [3..4)

    build_x_kernel<<<B * N, 128, 0, stream>>>(xy, load, demand, mask, embW, embb,
                                              wload, wdem, Wqf, Wql, xbuf);
    const int M  = B * N;
    const int MH = M / 2;
    for (int l = 0; l < NL; ++l) {
        dim3 g1(M / 64, 1);
        gemm_f32<false, false><<<g1, 256, 0, stream>>>(xbuf, Wk + (size_t)l * D * D, nullptr, kbuf, M, D, D);
        colmax_part<<<B * 8, 128, 0, stream>>>(kbuf, part);
        ek_inplace<<<B * 8, 128, 0, stream>>>(kbuf, part);
        gemm_f32<false, false><<<g1, 256, 0, stream>>>(xbuf, Wv + (size_t)l * D * D, nullptr, vbuf, M, D, D);
        gemm_f32<false, false><<<g1, 256, 0, stream>>>(xbuf, Wq + (size_t)l * D * D, nullptr, qbuf, M, D, D);
        attn_kernel<<<B * 16, 256, 0, stream>>>(pdist, mask, kbuf, vbuf, qbuf, nnum, aAttn, l, wbuf);
        ln_kernel<<<M / 4, 256, 0, stream>>>(xbuf, wbuf, ln1g + l * D, ln1b + l * D, xbuf);
        for (int h = 0; h < 2; ++h) {
            dim3 g2(MH / 64, FFH / 128);
            dim3 g3(MH / 64, 1);
            gemm_f32<true, true><<<g2, 256, 0, stream>>>(xbuf + (size_t)h * MH * D, fW1 + (size_t)l * D * FFH,
                                                         fb1 + l * FFH, bigh, MH, D, FFH);
            gemm_f32<true, false><<<g3, 256, 0, stream>>>(bigh, fW2 + (size_t)l * FFH * D,
                                                          fb2 + l * D, aux + (size_t)h * MH * D, MH, FFH, D);
        }
        ln_kernel<<<M / 4, 256, 0, stream>>>(xbuf, aux, ln2g + l * D, ln2b + l * D, xbuf);
    }
    k_final<<<B, 512, 0, stream>>>(xbuf, pdist, mask, nnum, nidx, aCom, out);
}

// Round 10
// 2129.217 us; speedup vs baseline: 7.7252x; 1.1856x over previous
//
#include <hip/hip_runtime.h>
#include <math.h>

constexpr int B   = 128;
constexpr int N   = 512;   // NNB + 2
constexpr int NNB = 510;
constexpr int D   = 128;
constexpr int FFH = 512;
constexpr int NL  = 3;

__device__ __forceinline__ float sigmoidf_(float x) { return 1.f / (1.f + expf(-x)); }

// ---------------------------------------------------------------------------
// XLA f32 FastTanh — exact tie structure of the jax reference. DO NOT TOUCH.
// ---------------------------------------------------------------------------
__device__ __forceinline__ float xla_fast_tanh(float x) {
    if (fabsf(x) < 0.0004f) return x;
    const float C = 7.99881172180175781f;
    float xc = fminf(fmaxf(x, -C), C);
    float x2 = __fmul_rn(xc, xc);
    float num = -2.76076847742355e-16f;
    num = __builtin_fmaf(x2, num, 2.00018790482477e-13f);
    num = __builtin_fmaf(x2, num, -8.60467152213735e-11f);
    num = __builtin_fmaf(x2, num, 5.12229709037114e-08f);
    num = __builtin_fmaf(x2, num, 1.48572235717979e-05f);
    num = __builtin_fmaf(x2, num, 6.37261928875436e-04f);
    num = __builtin_fmaf(x2, num, 4.89352455891786e-03f);
    num = __fmul_rn(xc, num);
    float den = 1.19825839466702e-06f;
    den = __builtin_fmaf(x2, den, 1.18534705686654e-04f);
    den = __builtin_fmaf(x2, den, 2.26843463243900e-03f);
    den = __builtin_fmaf(x2, den, 4.89352518554385e-03f);
    return num / den;
}

// ---------------------------------------------------------------------------
// Build x (B,N,D) f32.
// ---------------------------------------------------------------------------
__global__ __launch_bounds__(128) void build_x_kernel(
    const float* __restrict__ xy, const float* __restrict__ load,
    const float* __restrict__ demand, const float* __restrict__ mask,
    const float* __restrict__ embW, const float* __restrict__ embb,
    const float* __restrict__ wload, const float* __restrict__ wdem,
    const float* __restrict__ Wqf, const float* __restrict__ Wql,
    float* __restrict__ x)
{
    __shared__ float fln[128];
    const int bn = blockIdx.x;
    const int b  = bn >> 9;
    const int n  = bn & 511;
    const int d  = threadIdx.x;
    float l = load[b];
    float load3 = (l == 0.f) ? 1.f : l;

    if (n >= 2) {
        const int j = n - 2;
        float m = mask[(size_t)b * N + n];
        float out = 0.f;
        if (!(m < 0.f)) {
            float x0 = xy[(size_t)bn * 2 + 0];
            float x1 = xy[(size_t)bn * 2 + 1];
            float fl = x0 * embW[d] + x1 * embW[D + d] + embb[d];
            float dm = demand[(size_t)b * NNB + j] / load3;
            dm = fminf(fmaxf(dm, 0.f), 1.f);
            out = fl + dm * wdem[d];
        }
        x[(size_t)bn * D + d] = out;
    } else {
        float x0 = xy[(size_t)bn * 2 + 0];
        float x1 = xy[(size_t)bn * 2 + 1];
        fln[d] = x0 * embW[d] + x1 * embW[D + d] + embb[d];
        __syncthreads();
        const float* W = (n == 0) ? Wqf : Wql;
        float acc = 0.f;
        #pragma unroll 8
        for (int e = 0; e < D; ++e) acc = fmaf(fln[e], W[(size_t)e * D + d], acc);
        x[(size_t)bn * D + d] = acc + load3 * wload[d];
    }
}

// ---------------------------------------------------------------------------
// Tiled f32 GEMM: C = A @ W (+bias,+relu). 64x128 tile, BLK_K=32, 256 thr.
// ---------------------------------------------------------------------------
template<bool BIAS, bool RELU>
__global__ __launch_bounds__(256) void gemm_f32(
    const float* __restrict__ A, const float* __restrict__ W,
    const float* __restrict__ bias, float* __restrict__ C,
    int M, int K, int Nc)
{
    __shared__ float As[64][40];
    __shared__ float Ws[32][132];
    const int m0 = blockIdx.x * 64;
    const int n0 = blockIdx.y * 128;
    const int tid = threadIdx.x;
    const int tc = tid & 31;
    const int tr = tid >> 5;

    float4 acc[8];
    #pragma unroll
    for (int r = 0; r < 8; ++r) acc[r] = make_float4(0.f, 0.f, 0.f, 0.f);

    for (int kt = 0; kt < K; kt += 32) {
        #pragma unroll
        for (int i = 0; i < 2; ++i) {
            int f = tid + i * 256;
            int r = f >> 3, c4 = (f & 7) * 4;
            float4 av = *(const float4*)&A[(size_t)(m0 + r) * K + kt + c4];
            *(float4*)&As[r][c4] = av;
        }
        #pragma unroll
        for (int i = 0; i < 4; ++i) {
            int f = tid + i * 256;
            int r = f >> 5, c4 = (f & 31) * 4;
            float4 wv = *(const float4*)&W[(size_t)(kt + r) * Nc + n0 + c4];
            *(float4*)&Ws[r][c4] = wv;
        }
        __syncthreads();
        #pragma unroll
        for (int kk = 0; kk < 32; kk += 4) {
            float4 w0 = *(float4*)&Ws[kk + 0][tc * 4];
            float4 w1 = *(float4*)&Ws[kk + 1][tc * 4];
            float4 w2 = *(float4*)&Ws[kk + 2][tc * 4];
            float4 w3 = *(float4*)&Ws[kk + 3][tc * 4];
            #pragma unroll
            for (int r = 0; r < 8; ++r) {
                float4 a4 = *(float4*)&As[tr * 8 + r][kk];
                acc[r].x = fmaf(a4.x, w0.x, acc[r].x); acc[r].x = fmaf(a4.y, w1.x, acc[r].x);
                acc[r].x = fmaf(a4.z, w2.x, acc[r].x); acc[r].x = fmaf(a4.w, w3.x, acc[r].x);
                acc[r].y = fmaf(a4.x, w0.y, acc[r].y); acc[r].y = fmaf(a4.y, w1.y, acc[r].y);
                acc[r].y = fmaf(a4.z, w2.y, acc[r].y); acc[r].y = fmaf(a4.w, w3.y, acc[r].y);
                acc[r].z = fmaf(a4.x, w0.z, acc[r].z); acc[r].z = fmaf(a4.y, w1.z, acc[r].z);
                acc[r].z = fmaf(a4.z, w2.z, acc[r].z); acc[r].z = fmaf(a4.w, w3.z, acc[r].z);
                acc[r].w = fmaf(a4.x, w0.w, acc[r].w); acc[r].w = fmaf(a4.y, w1.w, acc[r].w);
                acc[r].w = fmaf(a4.z, w2.w, acc[r].w); acc[r].w = fmaf(a4.w, w3.w, acc[r].w);
            }
        }
        __syncthreads();
    }

    float4 bv = make_float4(0.f, 0.f, 0.f, 0.f);
    if (BIAS) bv = *(const float4*)&bias[n0 + tc * 4];
    #pragma unroll
    for (int r = 0; r < 8; ++r) {
        float4 o = acc[r];
        if (BIAS) { o.x += bv.x; o.y += bv.y; o.z += bv.z; o.w += bv.w; }
        if (RELU) {
            o.x = fmaxf(o.x, 0.f); o.y = fmaxf(o.y, 0.f);
            o.z = fmaxf(o.z, 0.f); o.w = fmaxf(o.w, 0.f);
        }
        *(float4*)&C[(size_t)(m0 + tr * 8 + r) * Nc + n0 + tc * 4] = o;
    }
}

// ---------------------------------------------------------------------------
// Column-max of k over s (axis=1), then ekv = [ek*v ; ek] (B,N,256).
// ---------------------------------------------------------------------------
__global__ __launch_bounds__(128) void colmax_part(
    const float* __restrict__ k, float* __restrict__ part)
{
    int b = blockIdx.x >> 3, c = blockIdx.x & 7, d = threadIdx.x;
    const float* kp = k + ((size_t)b * N + c * 64) * D + d;
    float m = -3.4e38f;
    #pragma unroll 8
    for (int s = 0; s < 64; ++s) m = fmaxf(m, kp[(size_t)s * D]);
    part[(size_t)blockIdx.x * D + d] = m;
}

__global__ __launch_bounds__(128) void ekv_build(
    const float* __restrict__ k, const float* __restrict__ v,
    const float* __restrict__ part, float* __restrict__ ekv)
{
    int b = blockIdx.x >> 3, c = blockIdx.x & 7, d = threadIdx.x;
    float m = -3.4e38f;
    #pragma unroll
    for (int j = 0; j < 8; ++j) m = fmaxf(m, part[((size_t)b * 8 + j) * D + d]);
    for (int s = 0; s < 64; ++s) {
        int sg = c * 64 + s;
        size_t off = ((size_t)b * N + sg) * D + d;
        float ek = expf(k[off] - m);
        size_t o2 = ((size_t)b * N + sg) * 256;
        ekv[o2 + d]       = ek * v[off];
        ekv[o2 + 128 + d] = ek;
    }
}

// ---------------------------------------------------------------------------
// Fused AAFM attention, per (b, 32-row tile):
//   ew = exp(la*pd + mask - rowmax) in padded LDS [32][516] (stride%32==4),
//   [num|den] = ew @ ekv (512x256): lane owns 4 unique cols (wave = 256 cols,
//   coalesced, no duplication), wave owns 8 rows, s unrolled x4 (float4 ew).
//   att = (sig(q)*num)/den via LDS den exchange.
// ---------------------------------------------------------------------------
__global__ __launch_bounds__(256) void attn_kernel(
    const float* __restrict__ pdist, const float* __restrict__ mask,
    const float* __restrict__ ekv, const float* __restrict__ q,
    const int* __restrict__ nnum, const float* __restrict__ alphaAttn, int layer,
    float* __restrict__ att)
{
    __shared__ float ew[32][516];
    __shared__ float red8[32][8];
    __shared__ float rmax[32];
    const int bt = blockIdx.x;
    const int b  = bt >> 4;
    const int t0 = (bt & 15) * 32;
    const int tid = threadIdx.x;
    const float la = -log2f((float)nnum[b]) * alphaAttn[layer];
    const float* pd = pdist + ((size_t)b * N + t0) * N;
    const float* mk = mask + (size_t)b * N;

    #pragma unroll
    for (int i = 0; i < 16; ++i) {
        int f = tid + i * 256;
        int r = f >> 7, s4 = (f & 127) * 4;
        float4 p = *(const float4*)&pd[(size_t)r * N + s4];
        float4 m = *(const float4*)&mk[s4];
        float4 w;
        w.x = fmaf(la, p.x, m.x); w.y = fmaf(la, p.y, m.y);
        w.z = fmaf(la, p.z, m.z); w.w = fmaf(la, p.w, m.w);
        *(float4*)&ew[r][s4] = w;
    }
    __syncthreads();
    {   // row max, stride-8 interleave: bank = (4r + j0 + 8j)%32 -> <=2-way
        int r = tid >> 3, j0 = tid & 7;
        float m = -3.4e38f;
        #pragma unroll 16
        for (int j = 0; j < 64; ++j) m = fmaxf(m, ew[r][j0 + 8 * j]);
        red8[r][j0] = m;
    }
    __syncthreads();
    if (tid < 32) {
        float m = red8[tid][0];
        #pragma unroll
        for (int j = 1; j < 8; ++j) m = fmaxf(m, red8[tid][j]);
        rmax[tid] = m;
    }
    __syncthreads();
    #pragma unroll
    for (int i = 0; i < 16; ++i) {
        int f = tid + i * 256;
        int r = f >> 7, s4 = (f & 127) * 4;
        float m = rmax[r];
        float4 w = *(float4*)&ew[r][s4];
        w.x = expf(w.x - m); w.y = expf(w.y - m);
        w.z = expf(w.z - m); w.w = expf(w.w - m);
        *(float4*)&ew[r][s4] = w;
    }
    __syncthreads();

    // ----- [num|den] = ew @ ekv -----
    const int lane = tid & 63;          // 64 lanes x 4 cols = 256 cols
    const int wv   = tid >> 6;          // wave -> 8 rows
    const int c4   = lane * 4;
    float4 acc[8];
    #pragma unroll
    for (int r = 0; r < 8; ++r) acc[r] = make_float4(0.f, 0.f, 0.f, 0.f);
    const float* ep = ekv + (size_t)b * N * 256 + c4;
    for (int s = 0; s < N; s += 4) {
        float4 e0 = *(const float4*)&ep[(size_t)(s + 0) * 256];
        float4 e1 = *(const float4*)&ep[(size_t)(s + 1) * 256];
        float4 e2 = *(const float4*)&ep[(size_t)(s + 2) * 256];
        float4 e3 = *(const float4*)&ep[(size_t)(s + 3) * 256];
        #pragma unroll
        for (int r = 0; r < 8; ++r) {
            float4 a = *(float4*)&ew[wv * 8 + r][s];
            acc[r].x = fmaf(a.x, e0.x, acc[r].x); acc[r].x = fmaf(a.y, e1.x, acc[r].x);
            acc[r].x = fmaf(a.z, e2.x, acc[r].x); acc[r].x = fmaf(a.w, e3.x, acc[r].x);
            acc[r].y = fmaf(a.x, e0.y, acc[r].y); acc[r].y = fmaf(a.y, e1.y, acc[r].y);
            acc[r].y = fmaf(a.z, e2.y, acc[r].y); acc[r].y = fmaf(a.w, e3.y, acc[r].y);
            acc[r].z = fmaf(a.x, e0.z, acc[r].z); acc[r].z = fmaf(a.y, e1.z, acc[r].z);
            acc[r].z = fmaf(a.z, e2.z, acc[r].z); acc[r].z = fmaf(a.w, e3.z, acc[r].z);
            acc[r].w = fmaf(a.x, e0.w, acc[r].w); acc[r].w = fmaf(a.y, e1.w, acc[r].w);
            acc[r].w = fmaf(a.z, e2.w, acc[r].w); acc[r].w = fmaf(a.w, e3.w, acc[r].w);
        }
    }
    __syncthreads();
    // den lanes (cols 128..255) stage into ew[row][c4-128]
    if (c4 >= 128) {
        #pragma unroll
        for (int r = 0; r < 8; ++r)
            *(float4*)&ew[wv * 8 + r][c4 - 128] = acc[r];
    }
    __syncthreads();
    if (c4 < 128) {
        #pragma unroll
        for (int r = 0; r < 8; ++r) {
            int row = wv * 8 + r;
            size_t off = ((size_t)b * N + t0 + row) * D + c4;
            float4 qq = *(const float4*)&q[off];
            float4 dd = *(float4*)&ew[row][c4];
            float4 o;
            o.x = sigmoidf_(qq.x) * acc[r].x / dd.x;
            o.y = sigmoidf_(qq.y) * acc[r].y / dd.y;
            o.z = sigmoidf_(qq.z) * acc[r].z / dd.z;
            o.w = sigmoidf_(qq.w) * acc[r].w / dd.w;
            *(float4*)&att[off] = o;
        }
    }
}

// ---------------------------------------------------------------------------
// out = LayerNorm(a + b) * g + be. Wave per row, two-pass variance.
// ---------------------------------------------------------------------------
__global__ __launch_bounds__(256) void ln_kernel(
    const float* a, const float* b2, const float* g, const float* be, float* out)
{
    int w = threadIdx.x >> 6, lane = threadIdx.x & 63;
    size_t row = (size_t)blockIdx.x * 4 + w;
    size_t base = row * D + lane * 2;
    float2 av = *(const float2*)&a[base];
    float2 bv = *(const float2*)&b2[base];
    float x0 = av.x + bv.x, x1 = av.y + bv.y;
    float s = x0 + x1;
    #pragma unroll
    for (int off = 32; off > 0; off >>= 1) s += __shfl_xor(s, off);
    float mean = s * (1.f / 128.f);
    float d0 = x0 - mean, d1 = x1 - mean;
    float ss = d0 * d0 + d1 * d1;
    #pragma unroll
    for (int off = 32; off > 0; off >>= 1) ss += __shfl_xor(ss, off);
    float rs = rsqrtf(ss * (1.f / 128.f) + 1e-5f);
    float2 o;
    o.x = d0 * rs * g[lane * 2]     + be[lane * 2];
    o.y = d1 * rs * g[lane * 2 + 1] + be[lane * 2 + 1];
    *(float2*)&out[base] = o;
}

// ---------------------------------------------------------------------------
// Final head (r8-validated): f64 score dot, XLA-f32 FastTanh, f32 softmax,
// first-occurrence argmax over p.
// ---------------------------------------------------------------------------
__global__ __launch_bounds__(512) void k_final(
    const float* __restrict__ x, const float* __restrict__ pdist,
    const float* __restrict__ mask, const int* __restrict__ nnum,
    const int* __restrict__ nidx, const float* __restrict__ aCom,
    float* __restrict__ out)
{
    __shared__ float  sc[512];
    __shared__ float  ee[512];
    __shared__ double qo[128];
    int b = blockIdx.x, tid = threadIdx.x;
    const float* xb = x + (size_t)b * N * D;
    if (tid < 128) qo[tid] = (double)xb[tid] + (double)xb[128 + tid];
    __syncthreads();
    if (tid < NNB) {
        const float* xr = xb + (size_t)(2 + tid) * 128;
        double s = 0.0;
        for (int dd = 0; dd < 128; ++dd) s += qo[dd] * (double)xr[dd];
        double lg = -log2((double)nnum[b]);
        s = s / 11.313708498984761
          + (double)aCom[0] * lg * (double)pdist[((size_t)b * 512 + 1) * 512 + 2 + tid];
        float t = xla_fast_tanh((float)s);
        sc[tid] = __fadd_rn(__fmul_rn(10.0f, t),
                            mask[(size_t)b * 512 + 2 + tid]);
    }
    __syncthreads();
    if (tid == 0) {
        float m = -3.4e38f;
        for (int n2 = 0; n2 < NNB; ++n2) m = fmaxf(m, sc[n2]);
        float S = 0.f;
        for (int n2 = 0; n2 < NNB; ++n2) {
            float e = expf(__fadd_rn(sc[n2], -m));
            ee[n2] = e;
            S = __fadd_rn(S, e);
        }
        float bestp = -1.f; int sel = 0;
        for (int n2 = 0; n2 < NNB; ++n2) {
            float p = ee[n2] / S;
            if (p > bestp) { bestp = p; sel = n2; }
        }
        out[b]     = (float)nidx[(size_t)b * NNB + sel];
        out[B + b] = bestp;
    }
}

// ---------------------------------------------------------------------------
extern "C" void kernel_launch(void* const* d_in, const int* in_sizes, int n_in,
                              void* d_out, int out_size, void* d_ws, size_t ws_size,
                              hipStream_t stream)
{
    const float* xy     = (const float*)d_in[0];
    const float* load   = (const float*)d_in[1];
    const float* demand = (const float*)d_in[2];
    const float* mask   = (const float*)d_in[3];
    const float* pdist  = (const float*)d_in[4];
    const int*   nnum   = (const int*)d_in[5];
    const int*   nidx   = (const int*)d_in[6];
    const float* embW   = (const float*)d_in[7];
    const float* embb   = (const float*)d_in[8];
    const float* wload  = (const float*)d_in[9];
    const float* wdem   = (const float*)d_in[10];
    const float* Wqf    = (const float*)d_in[11];
    const float* Wql    = (const float*)d_in[12];
    const float* aCom   = (const float*)d_in[13];
    const float* Wq     = (const float*)d_in[14];
    const float* Wk     = (const float*)d_in[15];
    const float* Wv     = (const float*)d_in[16];
    const float* aAttn  = (const float*)d_in[17];
    const float* ln1g   = (const float*)d_in[18];
    const float* ln1b   = (const float*)d_in[19];
    const float* ln2g   = (const float*)d_in[20];
    const float* ln2b   = (const float*)d_in[21];
    const float* fW1    = (const float*)d_in[22];
    const float* fb1    = (const float*)d_in[23];
    const float* fW2    = (const float*)d_in[24];
    const float* fb2    = (const float*)d_in[25];
    float* out = (float*)d_out;

    // Workspace: 6*SZ f32 = 192 MB (ws >= 224 MB proven by r6 sentinels).
    float* ws = (float*)d_ws;
    const size_t SZ = (size_t)B * N * D;      // 8388608 floats
    float* xbuf = ws;                         // slot 0
    float* qbuf = ws + SZ;                    // slot 1
    float* kbuf = ws + 2 * SZ;                // slot 2: raw k, then att out
    float* vbuf = ws + 3 * SZ;                // slot 3
    float* ekv  = ws + 4 * SZ;                // slots 4-5: [ek*v ; ek]
    float* part = qbuf;                       // colmax partials (pre-q-gemm)
    float* bigh = qbuf;                       // ff hidden: slots 1-2 (q,att dead)
    float* aux  = vbuf;                       // ff out: slot 3 (v dead)

    build_x_kernel<<<B * N, 128, 0, stream>>>(xy, load, demand, mask, embW, embb,
                                              wload, wdem, Wqf, Wql, xbuf);
    const int M  = B * N;
    const int MH = M / 2;
    for (int l = 0; l < NL; ++l) {
        dim3 g1(M / 64, 1);
        gemm_f32<false, false><<<g1, 256, 0, stream>>>(xbuf, Wk + (size_t)l * D * D, nullptr, kbuf, M, D, D);
        gemm_f32<false, false><<<g1, 256, 0, stream>>>(xbuf, Wv + (size_t)l * D * D, nullptr, vbuf, M, D, D);
        colmax_part<<<B * 8, 128, 0, stream>>>(kbuf, part);
        ekv_build<<<B * 8, 128, 0, stream>>>(kbuf, vbuf, part, ekv);
        gemm_f32<false, false><<<g1, 256, 0, stream>>>(xbuf, Wq + (size_t)l * D * D, nullptr, qbuf, M, D, D);
        attn_kernel<<<B * 16, 256, 0, stream>>>(pdist, mask, ekv, qbuf, nnum, aAttn, l, kbuf);
        ln_kernel<<<M / 4, 256, 0, stream>>>(xbuf, kbuf, ln1g + l * D, ln1b + l * D, xbuf);
        for (int h = 0; h < 2; ++h) {
            dim3 g2(MH / 64, FFH / 128);
            dim3 g3(MH / 64, 1);
            gemm_f32<true, true><<<g2, 256, 0, stream>>>(xbuf + (size_t)h * MH * D, fW1 + (size_t)l * D * FFH,
                                                         fb1 + l * FFH, bigh, MH, D, FFH);
            gemm_f32<true, false><<<g3, 256, 0, stream>>>(bigh, fW2 + (size_t)l * FFH * D,
                                                          fb2 + l * D, aux + (size_t)h * MH * D, MH, FFH, D);
        }
        ln_kernel<<<M / 4, 256, 0, stream>>>(xbuf, aux, ln2g + l * D, ln2b + l * D, xbuf);
    }
    k_final<<<B, 512, 0, stream>>>(xbuf, pdist, mask, nnum, nidx, aCom, out);
}